// Round 1
// baseline (2773.048 us; speedup 1.0000x reference)
//
#include <hip/hip_runtime.h>

// LSTM: x[64][512][512] fp32, U[512][4096], W[1024][4096], bias[4096]
// out = hidden_seq[64][512][1024] fp32 ++ h_T[64][1024] ++ c_T[64][1024]
//
// Phase A (parallel): cast x->f16; pack W,U into per-lane MFMA B-fragment order.
// Phase B (persistent, 256 WGs x 256 thr): 4 batch-groups x 16 batches; each group
//  = 64 WGs (one 16-wide h-column tile each); wave q computes gate section q.
// R4: seqlock-style tagged h exchange — ONE LLC round trip per timestep.
//  - hb element = 64-bit {tag = t+1 (hi), f16 h-pair (lo)} stored with a single
//    agent-scope atomic. Data IS the flag: no vmcnt(0) ack, no flag store, no
//    flag-poll round trip.
//  - consumer speculatively issues all 32 tagged loads right after S1 (latency
//    hidden under x@U MFMAs), then checks tags and re-loads only stale elements.
//  - slot-reuse safety: publish of h(t+2) (same slot parity as h(t)) is data-
//    dependent on consuming ALL of h(t+1), which is data-dependent on every WG
//    having finished reading slot t&1 — no extra sync needed.
//  - host memsets hb tags each launch (tags recur across graph replays by parity).

typedef _Float16 f16x8 __attribute__((ext_vector_type(8)));
typedef float f32x4 __attribute__((ext_vector_type(4)));

__device__ __forceinline__ unsigned short f2h_bits(float f) {
  union { _Float16 h; unsigned short u; } cv;
  cv.h = (_Float16)f;
  return cv.u;
}
__device__ __forceinline__ unsigned long long aload64(const unsigned long long* p) {
  return __hip_atomic_load(p, __ATOMIC_RELAXED, __HIP_MEMORY_SCOPE_AGENT);
}
__device__ __forceinline__ void astore64(unsigned long long* p, unsigned long long v) {
  __hip_atomic_store(p, v, __ATOMIC_RELAXED, __HIP_MEMORY_SCOPE_AGENT);
}

// ---- Phase A kernels ------------------------------------------------------

__global__ void cast_x_kernel(const float* __restrict__ x, unsigned short* __restrict__ xh) {
  int i = blockIdx.x * 256 + threadIdx.x;            // [0, 4194304)
  float4 v = ((const float4*)x)[i];
  ushort4 o;
  o.x = f2h_bits(v.x); o.y = f2h_bits(v.y);
  o.z = f2h_bits(v.z); o.w = f2h_bits(v.w);
  ((ushort4*)xh)[i] = o;
}

// Wp[((T*32+kt)*64+l)*8 + j] = f16(W[kt*32 + (l>>4)*8 + j][(T>>6)*1024 + (T&63)*16 + (l&15)])
__global__ void pack_W_kernel(const float* __restrict__ W, unsigned short* __restrict__ Wp) {
  int idx = blockIdx.x * 256 + threadIdx.x;          // [0, 524288)
  int l  = idx & 63;
  int kt = (idx >> 6) & 31;
  int T  = idx >> 11;                                // 0..255
  int q = T >> 6, jt = T & 63;
  int g  = q * 1024 + jt * 16 + (l & 15);
  int kb = kt * 32 + ((l >> 4) << 3);
  unsigned short tmp[8];
#pragma unroll
  for (int j = 0; j < 8; ++j) tmp[j] = f2h_bits(W[(size_t)(kb + j) * 4096 + g]);
  ((uint4*)Wp)[idx] = *(const uint4*)tmp;
}

__global__ void pack_U_kernel(const float* __restrict__ U, unsigned short* __restrict__ Up) {
  int idx = blockIdx.x * 256 + threadIdx.x;          // [0, 262144)
  int l  = idx & 63;
  int kt = (idx >> 6) & 15;
  int T  = idx >> 10;                                // 0..255
  int q = T >> 6, jt = T & 63;
  int g  = q * 1024 + jt * 16 + (l & 15);
  int kb = kt * 32 + ((l >> 4) << 3);
  unsigned short tmp[8];
#pragma unroll
  for (int j = 0; j < 8; ++j) tmp[j] = f2h_bits(U[(size_t)(kb + j) * 4096 + g]);
  ((uint4*)Up)[idx] = *(const uint4*)tmp;
}

// ---- Phase B: persistent recurrent kernel ---------------------------------

#define OUT_HS 33554432   // 64*512*1024

__global__ __launch_bounds__(256, 1) void lstm_rec_kernel(
    const unsigned short* __restrict__ xh,   // [64][512][512] f16
    const unsigned short* __restrict__ Wp,   // packed f16
    const unsigned short* __restrict__ Up,   // packed f16
    const float* __restrict__ bias,          // [4096]
    float* __restrict__ out,
    unsigned long long* hb)                  // [4 grp][2 slot][16][512] tagged pairs
{
  __shared__ unsigned short lx[2][16 * 520]; // x tiles, rows padded +8, double-buffered
  __shared__ unsigned short lh[16 * 1032];   // h tile, rows padded +8
  __shared__ float gl[4][16][16];            // gate exchange

  const int tid  = threadIdx.x;
  const int lane = tid & 63;
  const int wq   = tid >> 6;                 // wave id == gate section (i,f,g,o)
  const int m    = lane & 15;
  const int quad = lane >> 4;

  const int bx  = blockIdx.x;
  const int x8  = bx & 7;
  const int grp = x8 >> 1;                            // 0..3 batch group
  const int jt  = ((bx >> 3) << 1) | (x8 & 1);        // 0..63 h-column tile
  const int b0  = grp * 16;
  const int T   = wq * 64 + jt;

  // Register/AGPR-resident weight fragments
  f16x8 wf[32];
  {
    const f16x8* src = (const f16x8*)Wp + (size_t)T * 2048 + lane;
#pragma unroll
    for (int kt = 0; kt < 32; ++kt) wf[kt] = src[kt * 64];
  }
  f16x8 uf[16];
  {
    const f16x8* src = (const f16x8*)Up + (size_t)T * 1024 + lane;
#pragma unroll
    for (int k2 = 0; k2 < 16; ++k2) uf[k2] = src[k2 * 64];
  }
  const float bias_v = bias[wq * 1024 + jt * 16 + m];

  const int eb = tid >> 4, ej = tid & 15;    // epilogue: batch row / column
  const int b_out = b0 + eb;
  const int j_out = jt * 16 + ej;
  float c = 0.f;

  const uint2* xsrc = (const uint2*)xh;

  // Prologue: stage x(0) into lx[0]
  uint2 xr[8];
#pragma unroll
  for (int i = 0; i < 8; ++i) {
    int idx = tid + i * 256, row = idx >> 7, off = idx & 127;
    xr[i] = xsrc[(size_t)((b0 + row) * 512 + 0) * 128 + off];
  }
#pragma unroll
  for (int i = 0; i < 8; ++i) {
    int idx = tid + i * 256, row = idx >> 7, off = idx & 127;
    *(uint2*)&lx[0][row * 520 + off * 4] = xr[i];
  }

  unsigned long long va[16], vb[16];         // tagged h staging (fully unrolled idx)

  for (int t = 0; t < 512; ++t) {
    __syncthreads();                         // S1: lx[t&1] ready; gl(t-1) reads done

    // Prefetch x(t+1) into regs — shadowed by the tagged h-loads + x@U below.
    if (t < 511) {
#pragma unroll
      for (int i = 0; i < 8; ++i) {
        int idx = tid + i * 256, row = idx >> 7, off = idx & 127;
        xr[i] = xsrc[(size_t)((b0 + row) * 512 + (t + 1)) * 128 + off];
      }
    }

    const unsigned long long* hsrc =
        (const unsigned long long*)hb + (size_t)(grp * 2 + ((t - 1) & 1)) * 8192;
    if (t > 0) {
      // Speculative tagged h(t-1) load: issue ALL loads now, check after x@U.
#pragma unroll
      for (int i = 0; i < 16; ++i) {
        va[i] = aload64(hsrc + i * 512 + tid * 2);
        vb[i] = aload64(hsrc + i * 512 + tid * 2 + 1);
      }
    }

    f32x4 a0 = {bias_v, bias_v, bias_v, bias_v};
    f32x4 a1 = {0.f, 0.f, 0.f, 0.f};

    const unsigned short* lxt = lx[t & 1];
#pragma unroll
    for (int k2 = 0; k2 < 16; ++k2) {
      f16x8 xa = *(const f16x8*)&lxt[m * 520 + k2 * 32 + quad * 8];
      if (k2 & 1) a1 = __builtin_amdgcn_mfma_f32_16x16x32_f16(xa, uf[k2], a1, 0, 0, 0);
      else        a0 = __builtin_amdgcn_mfma_f32_16x16x32_f16(xa, uf[k2], a0, 0, 0, 0);
    }

    if (t > 0) {
      // Seqlock check: tag == t means the pair is h(t-1). Re-load only stale
      // elements; check phase is separate from issue phase so reloads pipeline.
      const unsigned int want = (unsigned int)t;
      for (;;) {
        bool ok = true;
#pragma unroll
        for (int i = 0; i < 16; ++i) {
          if ((unsigned int)(va[i] >> 32) != want) ok = false;
          if ((unsigned int)(vb[i] >> 32) != want) ok = false;
        }
        if (!__any((int)!ok)) break;
#pragma unroll
        for (int i = 0; i < 16; ++i) {
          if ((unsigned int)(va[i] >> 32) != want) va[i] = aload64(hsrc + i * 512 + tid * 2);
          if ((unsigned int)(vb[i] >> 32) != want) vb[i] = aload64(hsrc + i * 512 + tid * 2 + 1);
        }
      }

      // Stage h(t-1) pairs -> LDS (drop tags; i-th iteration stages row i)
#pragma unroll
      for (int i = 0; i < 16; ++i) {
        unsigned long long w = ((unsigned long long)(unsigned int)vb[i] << 32)
                             | (unsigned long long)(unsigned int)va[i];
        *(unsigned long long*)&lh[i * 1032 + tid * 4] = w;
      }
      __syncthreads();                       // B2: lh ready

#pragma unroll
      for (int kt = 0; kt < 32; ++kt) {
        f16x8 ha = *(const f16x8*)&lh[m * 1032 + kt * 32 + quad * 8];
        if (kt & 1) a1 = __builtin_amdgcn_mfma_f32_16x16x32_f16(ha, wf[kt], a1, 0, 0, 0);
        else        a0 = __builtin_amdgcn_mfma_f32_16x16x32_f16(ha, wf[kt], a0, 0, 0, 0);
      }
    }

    // Write next x tile into the other LDS buffer (loads long since complete).
    if (t < 511) {
#pragma unroll
      for (int i = 0; i < 8; ++i) {
        int idx = tid + i * 256, row = idx >> 7, off = idx & 127;
        *(uint2*)&lx[(t + 1) & 1][row * 520 + off * 4] = xr[i];
      }
    }

    // C/D layout: col = lane&15, row = quad*4 + r
#pragma unroll
    for (int r = 0; r < 4; ++r) gl[wq][quad * 4 + r][m] = a0[r] + a1[r];
    __syncthreads();                         // S3: gates ready

    float iv = gl[0][eb][ej], fv = gl[1][eb][ej];
    float gv = gl[2][eb][ej], ov = gl[3][eb][ej];
    float ig = 1.f / (1.f + __expf(-iv));
    float fg = 1.f / (1.f + __expf(-fv));
    float og = 1.f / (1.f + __expf(-ov));
    float e2g = __expf(2.f * gv);
    float gg = 1.f - 2.f / (e2g + 1.f);      // tanh, inf-safe
    c = fg * c + ig * gg;
    float e2c = __expf(2.f * c);
    float tc = 1.f - 2.f / (e2c + 1.f);
    float h = og * tc;

    out[(size_t)b_out * (512 * 1024) + (size_t)t * 1024 + j_out] = h;
    if (t == 511) {
      out[OUT_HS + b_out * 1024 + j_out] = h;
      out[OUT_HS + 65536 + b_out * 1024 + j_out] = c;
    } else {
      // Publish h(t): single 64-bit tagged store per pair — no ack, no flag.
      unsigned int hbits = (unsigned int)f2h_bits(h);
      unsigned int nbits = (unsigned int)__shfl_down((int)hbits, 1);
      if ((ej & 1) == 0) {
        unsigned long long pk = ((unsigned long long)(unsigned int)(t + 1) << 32)
                              | (unsigned long long)(hbits | (nbits << 16));
        unsigned long long* dst = hb + (size_t)(grp * 2 + (t & 1)) * 8192
                                + eb * 512 + jt * 8 + (ej >> 1);
        astore64(dst, pk);
      }
    }
  }
}

// ---- host-side launch -----------------------------------------------------

extern "C" void kernel_launch(void* const* d_in, const int* in_sizes, int n_in,
                              void* d_out, int out_size, void* d_ws, size_t ws_size,
                              hipStream_t stream) {
  const float* x    = (const float*)d_in[0];   // 64*512*512
  const float* U    = (const float*)d_in[1];   // 512*4096
  const float* W    = (const float*)d_in[2];   // 1024*4096
  const float* bias = (const float*)d_in[3];   // 4096
  float* out = (float*)d_out;

  char* p = (char*)d_ws;
  unsigned short* xh = (unsigned short*)p; p += (size_t)64 * 512 * 512 * 2;   // 33.5 MB
  unsigned short* Wp = (unsigned short*)p; p += (size_t)4096 * 1024 * 2;      //  8.4 MB
  unsigned short* Up = (unsigned short*)p; p += (size_t)4096 * 512 * 2;       //  4.2 MB
  unsigned long long* hb = (unsigned long long*)p;                            // 512 KB

  // Clear tags each launch: tag values recur across graph replays (same parity
  // slots hold the same tag set), so stale tags MUST be zeroed for correctness.
  hipMemsetAsync(hb, 0, (size_t)4 * 2 * 16 * 512 * 8, stream);
  cast_x_kernel<<<16384, 256, 0, stream>>>(x, xh);
  pack_W_kernel<<<2048, 256, 0, stream>>>(W, Wp);
  pack_U_kernel<<<1024, 256, 0, stream>>>(U, Up);
  lstm_rec_kernel<<<256, 256, 0, stream>>>(xh, Wp, Up, bias, out, hb);
}